// Round 1
// 617.652 us; speedup vs baseline: 1.0706x; 1.0706x over previous
//
#include <hip/hip_runtime.h>
#include <stdint.h>

typedef short short8 __attribute__((ext_vector_type(8)));
typedef unsigned short ushort8 __attribute__((ext_vector_type(8)));
typedef unsigned short ushort4v __attribute__((ext_vector_type(4)));
typedef float f32x4 __attribute__((ext_vector_type(4)));

#define HD 2048
#define S_LEN 2048
#define NROWS 8192
#define N3 6144

typedef __attribute__((address_space(3))) void lds_void_t;
typedef __attribute__((address_space(1))) void g_void_t;

__device__ inline void gload_lds16(const void* g, void* l) {
    __builtin_amdgcn_global_load_lds((g_void_t*)g, (lds_void_t*)l, 16, 0, 0);
}

__device__ inline unsigned short f2bf(float f) {
    unsigned u = __float_as_uint(f);
    unsigned r = (u + 0x7FFFu + ((u >> 16) & 1u)) >> 16;
    return (unsigned short)r;
}
__device__ inline float bf2f(unsigned short h) {
    return __uint_as_float(((unsigned)h) << 16);
}

// ---------------- LayerNorm fp32 -> bf16 ----------------
__global__ __launch_bounds__(256) void ln_kernel(const float* __restrict__ x,
    const float* __restrict__ gamma, const float* __restrict__ beta,
    unsigned short* __restrict__ xn) {
    int row = blockIdx.x;
    const float* xr = x + (size_t)row * HD;
    int tid = threadIdx.x;
    float v[8];
    float4 a = *(const float4*)(xr + tid * 8);
    float4 b = *(const float4*)(xr + tid * 8 + 4);
    v[0]=a.x; v[1]=a.y; v[2]=a.z; v[3]=a.w; v[4]=b.x; v[5]=b.y; v[6]=b.z; v[7]=b.w;
    float s = 0.f, ss = 0.f;
#pragma unroll
    for (int e = 0; e < 8; e++) { s += v[e]; ss += v[e] * v[e]; }
    for (int off = 32; off > 0; off >>= 1) {
        s += __shfl_down(s, off);
        ss += __shfl_down(ss, off);
    }
    __shared__ float red[10];
    int wave = tid >> 6, lane = tid & 63;
    if (lane == 0) { red[wave] = s; red[4 + wave] = ss; }
    __syncthreads();
    if (tid == 0) {
        float S = red[0] + red[1] + red[2] + red[3];
        float SS = red[4] + red[5] + red[6] + red[7];
        float mu = S * (1.0f / HD);
        float var = SS * (1.0f / HD) - mu * mu;
        red[8] = mu;
        red[9] = rsqrtf(var + 1e-5f);
    }
    __syncthreads();
    float mu = red[8], rstd = red[9];
#pragma unroll
    for (int e = 0; e < 8; e++) {
        int c = tid * 8 + e;
        float val = (v[e] - mu) * rstd * gamma[c] + beta[c];
        xn[(size_t)row * HD + c] = f2bf(val);
    }
}

// ---------------- transpose + cast fp32 -> bf16 ----------------
__global__ __launch_bounds__(256) void transp_f32_bf16(const float* __restrict__ src, int ld_s,
    unsigned short* __restrict__ dst, int ld_d) {
    __shared__ float tile[32][33];
    int c0 = blockIdx.x * 32, r0 = blockIdx.y * 32;
    int tc = threadIdx.x & 31, tr = threadIdx.x >> 5; // tr 0..7
#pragma unroll
    for (int i = 0; i < 32; i += 8)
        tile[tr + i][tc] = src[(size_t)(r0 + tr + i) * ld_s + c0 + tc];
    __syncthreads();
#pragma unroll
    for (int i = 0; i < 32; i += 8)
        dst[(size_t)(c0 + tr + i) * ld_d + r0 + tc] = f2bf(tile[tc][tr + i]);
}

// ---------------- causal softmax over bf16 scores, in place ----------------
__global__ __launch_bounds__(256) void softmax_causal(unsigned short* __restrict__ sc) {
    int r = blockIdx.x;            // 0..8191 = b*2048+s
    int s = r & (S_LEN - 1);
    unsigned short* row = sc + (size_t)r * S_LEN;
    int tid = threadIdx.x;
    ushort8 u = *(const ushort8*)(row + tid * 8);
    float v[8];
    float mx = -3.0e38f;
#pragma unroll
    for (int e = 0; e < 8; e++) {
        int t = tid * 8 + e;
        float f = bf2f(u[e]);
        v[e] = (t <= s) ? f : -3.0e38f;
        mx = fmaxf(mx, v[e]);
    }
    for (int off = 32; off > 0; off >>= 1) mx = fmaxf(mx, __shfl_down(mx, off));
    __shared__ float red[8];
    int wave = tid >> 6, lane = tid & 63;
    if (lane == 0) red[wave] = mx;
    __syncthreads();
    mx = fmaxf(fmaxf(red[0], red[1]), fmaxf(red[2], red[3]));
    float ex[8];
    float sum = 0.f;
#pragma unroll
    for (int e = 0; e < 8; e++) {
        ex[e] = (v[e] > -1.0e38f) ? __expf(v[e] - mx) : 0.f;
        sum += ex[e];
    }
    for (int off = 32; off > 0; off >>= 1) sum += __shfl_down(sum, off);
    if (lane == 0) red[4 + wave] = sum;
    __syncthreads();
    float inv = 1.0f / (red[4] + red[5] + red[6] + red[7]);
#pragma unroll
    for (int e = 0; e < 8; e++) {
        row[tid * 8 + e] = f2bf(ex[e] * inv);
    }
}

// ---------------- NT GEMM (128x128 tile) — kept for causal scores / PV ----------------
template <int EPI>
__global__ __launch_bounds__(256) void gemm_nt(
    const unsigned short* __restrict__ Ab, int lda, long sAz,
    const unsigned short* __restrict__ Bb, int ldb, long sBz,
    void* __restrict__ Cb, int ldc, long sCz,
    int kdim, int causal, float scale, const float* __restrict__ resid,
    unsigned short* __restrict__ vt) {
    int bx = blockIdx.x, by = blockIdx.y, bz = blockIdx.z;
    if (causal) by = gridDim.y - 1 - by;   // longest-first dispatch
    if (causal == 1 && bx > by) return;
    const unsigned short* A = Ab + (size_t)bz * sAz;
    const unsigned short* Bt = Bb + (size_t)bz * sBz;
    int kmax = kdim;
    if (causal == 2) { int km = (by + 1) * 128; if (km < kmax) kmax = km; }
    int m0 = by * 128, n0 = bx * 128;

    __shared__ unsigned short lA[128 * 64];
    __shared__ unsigned short lB[128 * 64];

    int tid = threadIdx.x;
    int wave = tid >> 6, lane = tid & 63;
    int quad = lane >> 4, l16 = lane & 15;
    int wr = wave >> 1, wc = wave & 1;

    int rstage = wave * 32 + (lane >> 2);
    int ck = (lane & 3) * 8;
    const unsigned short* gA[2][2];
    const unsigned short* gB[2][2];
    unsigned short* ldA[2][2];
    unsigned short* ldB[2][2];
#pragma unroll
    for (int r16 = 0; r16 < 2; r16++)
#pragma unroll
        for (int h = 0; h < 2; h++) {
            gA[r16][h] = A + (size_t)(m0 + rstage + r16 * 16) * lda + h * 32 + ck;
            gB[r16][h] = Bt + (size_t)(n0 + rstage + r16 * 16) * ldb + h * 32 + ck;
            ldA[r16][h] = &lA[h * 4096 + (wave * 32 + r16 * 16) * 32];
            ldB[r16][h] = &lB[h * 4096 + (wave * 32 + r16 * 16) * 32];
        }

    f32x4 acc[4][4] = {};

    for (int k0 = 0; k0 < kmax; k0 += 64) {
        __syncthreads();
#pragma unroll
        for (int r16 = 0; r16 < 2; r16++)
#pragma unroll
            for (int h = 0; h < 2; h++) {
                gload_lds16(gA[r16][h], ldA[r16][h]);
                gload_lds16(gB[r16][h], ldB[r16][h]);
            }
        __syncthreads();
#pragma unroll
        for (int h = 0; h < 2; h++) {
            short8 af[4], bfr[4];
#pragma unroll
            for (int i = 0; i < 4; i++)
                af[i] = *(const short8*)&lA[h * 4096 + (wr * 64 + i * 16 + l16) * 32 + quad * 8];
#pragma unroll
            for (int j = 0; j < 4; j++)
                bfr[j] = *(const short8*)&lB[h * 4096 + (wc * 64 + j * 16 + l16) * 32 + quad * 8];
#pragma unroll
            for (int i = 0; i < 4; i++)
#pragma unroll
                for (int j = 0; j < 4; j++)
                    acc[i][j] = __builtin_amdgcn_mfma_f32_16x16x32_bf16(af[i], bfr[j], acc[i][j], 0, 0, 0);
        }
#pragma unroll
        for (int r16 = 0; r16 < 2; r16++)
#pragma unroll
            for (int h = 0; h < 2; h++) { gA[r16][h] += 64; gB[r16][h] += 64; }
    }

    int row0 = m0 + wr * 64 + quad * 4;
    int col0 = n0 + wc * 64 + l16;
    if (EPI == 3 && n0 >= 4096) {
        int batch = m0 >> 11;
        int sl0 = (m0 & 2047) + wr * 64 + quad * 4;
#pragma unroll
        for (int j = 0; j < 4; j++) {
            int kcol = (n0 - 4096) + wc * 64 + j * 16 + l16;
            unsigned short* base = vt + (size_t)batch * S_LEN * S_LEN + (size_t)kcol * S_LEN + sl0;
#pragma unroll
            for (int i = 0; i < 4; i++) {
                ushort4v p;
#pragma unroll
                for (int r = 0; r < 4; r++) p[r] = f2bf(acc[i][j][r]);
                *(ushort4v*)(base + i * 16) = p;
            }
        }
    } else if (EPI == 0 || EPI == 1 || EPI == 3) {
        unsigned short* C = (unsigned short*)Cb + (size_t)bz * sCz;
#pragma unroll
        for (int i = 0; i < 4; i++)
#pragma unroll
            for (int r = 0; r < 4; r++) {
                int row = row0 + i * 16 + r;
#pragma unroll
                for (int j = 0; j < 4; j++) {
                    float v = acc[i][j][r];
                    if (EPI == 1) v *= scale;
                    C[(size_t)row * ldc + col0 + j * 16] = f2bf(v);
                }
            }
    } else {
        float* C = (float*)Cb + (size_t)bz * sCz;
#pragma unroll
        for (int i = 0; i < 4; i++)
#pragma unroll
            for (int r = 0; r < 4; r++) {
                int row = row0 + i * 16 + r;
#pragma unroll
                for (int j = 0; j < 4; j++) {
                    int col = col0 + j * 16;
                    C[(size_t)row * ldc + col] = acc[i][j][r] + resid[(size_t)row * ldc + col];
                }
            }
    }
}

// ================= 256x256 pipelined NT GEMM (8 waves, BK=32, 4-deep LDS ring) =================
// C[m,n] = sum_k A[m,k]*Bt[n,k].  Requires: M%256==0, N%256==0, K%32==0, K>=96, grid%8==0.
// LDS panels swizzled: byte ^= ((row&7)<<4).  global_load_lds dest is LINEAR; the per-lane
// GLOBAL source is inverse-swizzled so swizzled ds_read finds its data (guide rule #21).
// Counted vmcnt(8) at each tile boundary — prefetch distance 3 tiles, never drains to 0.
// EPI 2: fp32 store + residual.  EPI 3: bf16 store (n<4096) / packed-transposed vt (n>=4096).
template <int EPI>
__global__ __launch_bounds__(512, 2) void gemm256_nt(
    const unsigned short* __restrict__ A, int lda,
    const unsigned short* __restrict__ Bt, int ldb,
    void* __restrict__ Cb, int ldc,
    int kdim, int nbx,
    const float* __restrict__ resid, unsigned short* __restrict__ vt) {

    __shared__ unsigned short lds[4][2][8192];   // [ring buf][A,B][256 rows x 32 k] = 128 KiB

    // XCD-aware bijective block swizzle (grid % 8 == 0)
    unsigned id = blockIdx.x;
    unsigned nwg = gridDim.x;
    unsigned wg = (id & 7u) * (nwg >> 3) + (id >> 3);
    int bx = (int)(wg % (unsigned)nbx), by = (int)(wg / (unsigned)nbx);
    int m0 = by * 256, n0 = bx * 256;

    int tid = threadIdx.x;
    int wave = tid >> 6, lane = tid & 63;
    int quad = lane >> 4, l16 = lane & 15;
    int wr = wave >> 2, wc = wave & 3;           // 2 x 4 wave grid; per-wave C = 128 x 64

    // read-side swizzled lane offset within a panel: S(row,quad) = (row*64+quad*16) ^ ((row&7)<<4)
    // (row&7) == (l16&7) for all fragment rows, so the XOR part is a lane constant.
    int laneoff = (l16 * 64 + quad * 16) ^ ((l16 & 7) << 4);

    // stage-side inverse swizzle: thread tid fills linear LDS bytes [tid*16, tid*16+16)
    int q = tid >> 2;
    int rsw = q ^ ((q >> 2) & 1);                // source row (within 128-row half)
    int scol = ((tid & 3) ^ (rsw & 3)) << 3;     // source k-start (elements)
    const unsigned short* gA0 = A + (size_t)(m0 + rsw) * lda + scol;
    const unsigned short* gA1 = A + (size_t)(m0 + 128 + rsw) * lda + scol;
    const unsigned short* gB0 = Bt + (size_t)(n0 + rsw) * ldb + scol;
    const unsigned short* gB1 = Bt + (size_t)(n0 + 128 + rsw) * ldb + scol;

    int nkt = kdim >> 5;                         // K tiles of 32

    // prologue: stage tiles 0..2 into bufs 0..2 (FIFO order matters for vmcnt ledger)
#pragma unroll
    for (int u = 0; u < 3; ++u) {
        if (u < nkt) {
            char* dA = (char*)&lds[u][0][0] + wave * 1024;
            char* dB = (char*)&lds[u][1][0] + wave * 1024;
            gload_lds16(gA0 + u * 32, dA);
            gload_lds16(gA1 + u * 32, dA + 8192);
            gload_lds16(gB0 + u * 32, dB);
            gload_lds16(gB1 + u * 32, dB + 8192);
        }
    }
    gA0 += 96; gA1 += 96; gB0 += 96; gB1 += 96;  // next tile to stage = 3
    if (nkt > 2)      asm volatile("s_waitcnt vmcnt(8)" ::: "memory");
    else if (nkt > 1) asm volatile("s_waitcnt vmcnt(4)" ::: "memory");
    else              asm volatile("s_waitcnt vmcnt(0)" ::: "memory");
    __builtin_amdgcn_s_barrier();

    f32x4 acc[8][4] = {};

    for (int t = 0; t < nkt; ++t) {
        int buf = t & 3, sbuf = (t + 3) & 3;
        const char* lA = (const char*)&lds[buf][0][0];
        const char* lB = (const char*)&lds[buf][1][0];
        bool do_stage = (t + 3 < nkt);

        // ---- phase A: quadrants i=0..3, all j; stage A-halves of tile t+3 ----
        short8 af[4], bfr[4];
#pragma unroll
        for (int i = 0; i < 4; ++i)
            af[i] = *(const short8*)(lA + wr * 8192 + i * 1024 + laneoff);
#pragma unroll
        for (int j = 0; j < 4; ++j)
            bfr[j] = *(const short8*)(lB + wc * 4096 + j * 1024 + laneoff);
        if (do_stage) {
            char* dA = (char*)&lds[sbuf][0][0] + wave * 1024;
            gload_lds16(gA0, dA);
            gload_lds16(gA1, dA + 8192);
        }
        __builtin_amdgcn_s_barrier();
        __builtin_amdgcn_s_setprio(1);
#pragma unroll
        for (int i = 0; i < 4; ++i)
#pragma unroll
            for (int j = 0; j < 4; ++j)
                acc[i][j] = __builtin_amdgcn_mfma_f32_16x16x32_bf16(af[i], bfr[j], acc[i][j], 0, 0, 0);
        __builtin_amdgcn_s_setprio(0);
        __builtin_amdgcn_s_barrier();

        // ---- phase B: quadrants i=4..7 (reuse bfr); stage B-halves of tile t+3 ----
        short8 ag[4];
#pragma unroll
        for (int i = 0; i < 4; ++i)
            ag[i] = *(const short8*)(lA + wr * 8192 + (4 + i) * 1024 + laneoff);
        if (do_stage) {
            char* dB = (char*)&lds[sbuf][1][0] + wave * 1024;
            gload_lds16(gB0, dB);
            gload_lds16(gB1, dB + 8192);
        }
        // tile t+1 must be resident before next iteration reads it.
        // outstanding ledger: tiles t+2, t+3 in flight (4 loads each) -> counted wait.
        if (t + 3 < nkt)      asm volatile("s_waitcnt vmcnt(8)" ::: "memory");
        else if (t + 2 < nkt) asm volatile("s_waitcnt vmcnt(4)" ::: "memory");
        else if (t + 1 < nkt) asm volatile("s_waitcnt vmcnt(0)" ::: "memory");
        __builtin_amdgcn_s_barrier();
        __builtin_amdgcn_s_setprio(1);
#pragma unroll
        for (int i = 0; i < 4; ++i)
#pragma unroll
            for (int j = 0; j < 4; ++j)
                acc[4 + i][j] = __builtin_amdgcn_mfma_f32_16x16x32_bf16(ag[i], bfr[j], acc[4 + i][j], 0, 0, 0);
        __builtin_amdgcn_s_setprio(0);
        __builtin_amdgcn_s_barrier();

        gA0 += 32; gA1 += 32; gB0 += 32; gB1 += 32;
    }

    // ---- epilogue ----
    if (EPI == 3 && n0 >= 4096) {
        // v columns: transposed into vt[batch][kcol][s], packed 4 s-values
        int batch = m0 >> 11;
        int sl0 = (m0 & 2047) + wr * 128 + quad * 4;
#pragma unroll
        for (int j = 0; j < 4; ++j) {
            int kcol = (n0 - 4096) + wc * 64 + j * 16 + l16;
            unsigned short* base = vt + (size_t)batch * S_LEN * S_LEN + (size_t)kcol * S_LEN + sl0;
#pragma unroll
            for (int i = 0; i < 8; ++i) {
                ushort4v p;
#pragma unroll
                for (int r = 0; r < 4; ++r) p[r] = f2bf(acc[i][j][r]);
                *(ushort4v*)(base + i * 16) = p;
            }
        }
    } else if (EPI == 3) {
        unsigned short* C = (unsigned short*)Cb;
#pragma unroll
        for (int i = 0; i < 8; ++i)
#pragma unroll
            for (int r = 0; r < 4; ++r) {
                int row = m0 + wr * 128 + i * 16 + quad * 4 + r;
#pragma unroll
                for (int j = 0; j < 4; ++j)
                    C[(size_t)row * ldc + n0 + wc * 64 + j * 16 + l16] = f2bf(acc[i][j][r]);
            }
    } else { // EPI == 2: fp32 + residual
        float* C = (float*)Cb;
#pragma unroll
        for (int i = 0; i < 8; ++i)
#pragma unroll
            for (int r = 0; r < 4; ++r) {
                int row = m0 + wr * 128 + i * 16 + quad * 4 + r;
#pragma unroll
                for (int j = 0; j < 4; ++j) {
                    int col = n0 + wc * 64 + j * 16 + l16;
                    C[(size_t)row * ldc + col] = acc[i][j][r] + resid[(size_t)row * ldc + col];
                }
            }
    }
}

extern "C" void kernel_launch(void* const* d_in, const int* in_sizes, int n_in,
                              void* d_out, int out_size, void* d_ws, size_t ws_size,
                              hipStream_t stream) {
    const float* x      = (const float*)d_in[0];   // [4,2048,2048]
    const float* qkv    = (const float*)d_in[1];   // [2048,6144]
    const float* o_proj = (const float*)d_in[2];   // [2048,2048]
    const float* gamma  = (const float*)d_in[3];
    const float* beta   = (const float*)d_in[4];
    float* out = (float*)d_out;                    // [8192,2048]

    char* w = (char*)d_ws;
    unsigned short* xn      = (unsigned short*)(w);              // 33,554,432 B [8192,2048]; later aliased as scores
    unsigned short* w_t     = (unsigned short*)(w + 33554432);   // 25,165,824 B [6144,2048] qkv^T
    unsigned short* o_t     = (unsigned short*)(w + 58720256);   //  8,388,608 B [2048,2048] o_proj^T
    unsigned short* qkv_out = (unsigned short*)(w + 67108864);   // 100,663,296 B [8192,6144] q|k (v slot unused; q slot reused for attn_out)
    unsigned short* v_t     = (unsigned short*)(w + 167772160);  // 33,554,432 B [4][2048,2048] v^T (written directly by GEMM1)
    unsigned short* scores  = xn;                                // alias: x_norm dead after GEMM1

    // 1) LayerNorm + cast
    ln_kernel<<<NROWS, 256, 0, stream>>>(x, gamma, beta, xn);
    // 2) weight transposes + cast
    transp_f32_bf16<<<dim3(192, 64), 256, 0, stream>>>(qkv, N3, w_t, HD);
    transp_f32_bf16<<<dim3(64, 64), 256, 0, stream>>>(o_proj, HD, o_t, HD);
    // 3) QKV projection: [8192,2048] @ [2048,6144] via 256^2 pipelined GEMM
    //    q,k row-major bf16, v written transposed to v_t.  grid = 24x32 = 768 (%8==0)
    gemm256_nt<3><<<dim3(768), 512, 0, stream>>>(xn, HD, w_t, HD,
        (void*)qkv_out, N3, HD, 24, nullptr, v_t);
    // 4) scores = q @ k^T * scale (skip upper-triangle blocks, longest rows first)
    float scale = 0.022097086912079608f; // 1/sqrt(2048)
    gemm_nt<1><<<dim3(16, 16, 4), 256, 0, stream>>>(qkv_out, N3, (long)S_LEN * N3,
        qkv_out + 2048, N3, (long)S_LEN * N3,
        (void*)scores, S_LEN, (long)S_LEN * S_LEN, HD, 1, scale, nullptr, nullptr);
    // 5) causal softmax in place (zeroes t>s so PV GEMM reads clean zeros)
    softmax_causal<<<NROWS, 256, 0, stream>>>(scores);
    // 6) attn_out = P @ V  (K clipped at diagonal block, longest-first), into q slot of qkv_out
    gemm_nt<0><<<dim3(16, 16, 4), 256, 0, stream>>>(scores, S_LEN, (long)S_LEN * S_LEN,
        v_t, S_LEN, (long)HD * S_LEN,
        (void*)qkv_out, N3, (long)S_LEN * N3, S_LEN, 2, 1.0f, nullptr, nullptr);
    // 7) out = attn_out @ o_proj + x (fp32) via 256^2 pipelined GEMM; grid = 8x32 = 256
    gemm256_nt<2><<<dim3(256), 512, 0, stream>>>(qkv_out, N3, o_t, HD,
        (void*)out, HD, HD, 8, x, nullptr);
}

// Round 2
// 607.126 us; speedup vs baseline: 1.0891x; 1.0173x over previous
//
#include <hip/hip_runtime.h>
#include <stdint.h>

typedef short short8 __attribute__((ext_vector_type(8)));
typedef unsigned short ushort8 __attribute__((ext_vector_type(8)));
typedef unsigned short ushort4v __attribute__((ext_vector_type(4)));
typedef float f32x4 __attribute__((ext_vector_type(4)));

#define HD 2048
#define S_LEN 2048
#define NROWS 8192
#define N3 6144

typedef __attribute__((address_space(3))) void lds_void_t;
typedef __attribute__((address_space(1))) void g_void_t;

__device__ inline void gload_lds16(const void* g, void* l) {
    __builtin_amdgcn_global_load_lds((g_void_t*)g, (lds_void_t*)l, 16, 0, 0);
}

__device__ inline unsigned short f2bf(float f) {
    unsigned u = __float_as_uint(f);
    unsigned r = (u + 0x7FFFu + ((u >> 16) & 1u)) >> 16;
    return (unsigned short)r;
}
__device__ inline float bf2f(unsigned short h) {
    return __uint_as_float(((unsigned)h) << 16);
}

// ---------------- LayerNorm fp32 -> bf16 ----------------
__global__ __launch_bounds__(256) void ln_kernel(const float* __restrict__ x,
    const float* __restrict__ gamma, const float* __restrict__ beta,
    unsigned short* __restrict__ xn) {
    int row = blockIdx.x;
    const float* xr = x + (size_t)row * HD;
    int tid = threadIdx.x;
    float v[8];
    float4 a = *(const float4*)(xr + tid * 8);
    float4 b = *(const float4*)(xr + tid * 8 + 4);
    v[0]=a.x; v[1]=a.y; v[2]=a.z; v[3]=a.w; v[4]=b.x; v[5]=b.y; v[6]=b.z; v[7]=b.w;
    float s = 0.f, ss = 0.f;
#pragma unroll
    for (int e = 0; e < 8; e++) { s += v[e]; ss += v[e] * v[e]; }
    for (int off = 32; off > 0; off >>= 1) {
        s += __shfl_down(s, off);
        ss += __shfl_down(ss, off);
    }
    __shared__ float red[10];
    int wave = tid >> 6, lane = tid & 63;
    if (lane == 0) { red[wave] = s; red[4 + wave] = ss; }
    __syncthreads();
    if (tid == 0) {
        float S = red[0] + red[1] + red[2] + red[3];
        float SS = red[4] + red[5] + red[6] + red[7];
        float mu = S * (1.0f / HD);
        float var = SS * (1.0f / HD) - mu * mu;
        red[8] = mu;
        red[9] = rsqrtf(var + 1e-5f);
    }
    __syncthreads();
    float mu = red[8], rstd = red[9];
#pragma unroll
    for (int e = 0; e < 8; e++) {
        int c = tid * 8 + e;
        float val = (v[e] - mu) * rstd * gamma[c] + beta[c];
        xn[(size_t)row * HD + c] = f2bf(val);
    }
}

// ---------------- transpose + cast fp32 -> bf16 ----------------
__global__ __launch_bounds__(256) void transp_f32_bf16(const float* __restrict__ src, int ld_s,
    unsigned short* __restrict__ dst, int ld_d) {
    __shared__ float tile[32][33];
    int c0 = blockIdx.x * 32, r0 = blockIdx.y * 32;
    int tc = threadIdx.x & 31, tr = threadIdx.x >> 5; // tr 0..7
#pragma unroll
    for (int i = 0; i < 32; i += 8)
        tile[tr + i][tc] = src[(size_t)(r0 + tr + i) * ld_s + c0 + tc];
    __syncthreads();
#pragma unroll
    for (int i = 0; i < 32; i += 8)
        dst[(size_t)(c0 + tr + i) * ld_d + r0 + tc] = f2bf(tile[tc][tr + i]);
}

// ---------------- causal softmax over bf16 scores, in place ----------------
__global__ __launch_bounds__(256) void softmax_causal(unsigned short* __restrict__ sc) {
    int r = blockIdx.x;            // 0..8191 = b*2048+s
    int s = r & (S_LEN - 1);
    unsigned short* row = sc + (size_t)r * S_LEN;
    int tid = threadIdx.x;
    ushort8 u = *(const ushort8*)(row + tid * 8);
    float v[8];
    float mx = -3.0e38f;
#pragma unroll
    for (int e = 0; e < 8; e++) {
        int t = tid * 8 + e;
        float f = bf2f(u[e]);
        v[e] = (t <= s) ? f : -3.0e38f;
        mx = fmaxf(mx, v[e]);
    }
    for (int off = 32; off > 0; off >>= 1) mx = fmaxf(mx, __shfl_down(mx, off));
    __shared__ float red[8];
    int wave = tid >> 6, lane = tid & 63;
    if (lane == 0) red[wave] = mx;
    __syncthreads();
    mx = fmaxf(fmaxf(red[0], red[1]), fmaxf(red[2], red[3]));
    float ex[8];
    float sum = 0.f;
#pragma unroll
    for (int e = 0; e < 8; e++) {
        ex[e] = (v[e] > -1.0e38f) ? __expf(v[e] - mx) : 0.f;
        sum += ex[e];
    }
    for (int off = 32; off > 0; off >>= 1) sum += __shfl_down(sum, off);
    if (lane == 0) red[4 + wave] = sum;
    __syncthreads();
    float inv = 1.0f / (red[4] + red[5] + red[6] + red[7]);
#pragma unroll
    for (int e = 0; e < 8; e++) {
        row[tid * 8 + e] = f2bf(ex[e] * inv);
    }
}

// ---------------- NT GEMM (128x128 tile) — kept for causal scores / PV ----------------
template <int EPI>
__global__ __launch_bounds__(256) void gemm_nt(
    const unsigned short* __restrict__ Ab, int lda, long sAz,
    const unsigned short* __restrict__ Bb, int ldb, long sBz,
    void* __restrict__ Cb, int ldc, long sCz,
    int kdim, int causal, float scale, const float* __restrict__ resid,
    unsigned short* __restrict__ vt) {
    int bx = blockIdx.x, by = blockIdx.y, bz = blockIdx.z;
    if (causal) by = gridDim.y - 1 - by;   // longest-first dispatch
    if (causal == 1 && bx > by) return;
    const unsigned short* A = Ab + (size_t)bz * sAz;
    const unsigned short* Bt = Bb + (size_t)bz * sBz;
    int kmax = kdim;
    if (causal == 2) { int km = (by + 1) * 128; if (km < kmax) kmax = km; }
    int m0 = by * 128, n0 = bx * 128;

    __shared__ unsigned short lA[128 * 64];
    __shared__ unsigned short lB[128 * 64];

    int tid = threadIdx.x;
    int wave = tid >> 6, lane = tid & 63;
    int quad = lane >> 4, l16 = lane & 15;
    int wr = wave >> 1, wc = wave & 1;

    int rstage = wave * 32 + (lane >> 2);
    int ck = (lane & 3) * 8;
    const unsigned short* gA[2][2];
    const unsigned short* gB[2][2];
    unsigned short* ldA[2][2];
    unsigned short* ldB[2][2];
#pragma unroll
    for (int r16 = 0; r16 < 2; r16++)
#pragma unroll
        for (int h = 0; h < 2; h++) {
            gA[r16][h] = A + (size_t)(m0 + rstage + r16 * 16) * lda + h * 32 + ck;
            gB[r16][h] = Bt + (size_t)(n0 + rstage + r16 * 16) * ldb + h * 32 + ck;
            ldA[r16][h] = &lA[h * 4096 + (wave * 32 + r16 * 16) * 32];
            ldB[r16][h] = &lB[h * 4096 + (wave * 32 + r16 * 16) * 32];
        }

    f32x4 acc[4][4] = {};

    for (int k0 = 0; k0 < kmax; k0 += 64) {
        __syncthreads();
#pragma unroll
        for (int r16 = 0; r16 < 2; r16++)
#pragma unroll
            for (int h = 0; h < 2; h++) {
                gload_lds16(gA[r16][h], ldA[r16][h]);
                gload_lds16(gB[r16][h], ldB[r16][h]);
            }
        __syncthreads();
#pragma unroll
        for (int h = 0; h < 2; h++) {
            short8 af[4], bfr[4];
#pragma unroll
            for (int i = 0; i < 4; i++)
                af[i] = *(const short8*)&lA[h * 4096 + (wr * 64 + i * 16 + l16) * 32 + quad * 8];
#pragma unroll
            for (int j = 0; j < 4; j++)
                bfr[j] = *(const short8*)&lB[h * 4096 + (wc * 64 + j * 16 + l16) * 32 + quad * 8];
#pragma unroll
            for (int i = 0; i < 4; i++)
#pragma unroll
                for (int j = 0; j < 4; j++)
                    acc[i][j] = __builtin_amdgcn_mfma_f32_16x16x32_bf16(af[i], bfr[j], acc[i][j], 0, 0, 0);
        }
#pragma unroll
        for (int r16 = 0; r16 < 2; r16++)
#pragma unroll
            for (int h = 0; h < 2; h++) { gA[r16][h] += 64; gB[r16][h] += 64; }
    }

    int row0 = m0 + wr * 64 + quad * 4;
    int col0 = n0 + wc * 64 + l16;
    if (EPI == 3 && n0 >= 4096) {
        int batch = m0 >> 11;
        int sl0 = (m0 & 2047) + wr * 64 + quad * 4;
#pragma unroll
        for (int j = 0; j < 4; j++) {
            int kcol = (n0 - 4096) + wc * 64 + j * 16 + l16;
            unsigned short* base = vt + (size_t)batch * S_LEN * S_LEN + (size_t)kcol * S_LEN + sl0;
#pragma unroll
            for (int i = 0; i < 4; i++) {
                ushort4v p;
#pragma unroll
                for (int r = 0; r < 4; r++) p[r] = f2bf(acc[i][j][r]);
                *(ushort4v*)(base + i * 16) = p;
            }
        }
    } else if (EPI == 0 || EPI == 1 || EPI == 3) {
        unsigned short* C = (unsigned short*)Cb + (size_t)bz * sCz;
#pragma unroll
        for (int i = 0; i < 4; i++)
#pragma unroll
            for (int r = 0; r < 4; r++) {
                int row = row0 + i * 16 + r;
#pragma unroll
                for (int j = 0; j < 4; j++) {
                    float v = acc[i][j][r];
                    if (EPI == 1) v *= scale;
                    C[(size_t)row * ldc + col0 + j * 16] = f2bf(v);
                }
            }
    } else {
        float* C = (float*)Cb + (size_t)bz * sCz;
#pragma unroll
        for (int i = 0; i < 4; i++)
#pragma unroll
            for (int r = 0; r < 4; r++) {
                int row = row0 + i * 16 + r;
#pragma unroll
                for (int j = 0; j < 4; j++) {
                    int col = col0 + j * 16;
                    C[(size_t)row * ldc + col] = acc[i][j][r] + resid[(size_t)row * ldc + col];
                }
            }
    }
}

// ================= 256x256 pipelined NT GEMM (8 waves, BK=32, 4-deep LDS ring) =================
// v2: ONE barrier per K-tile.  Hazard ledger:
//   - reads(t) need all waves' tile-t loads resident: each wave does counted vmcnt
//     (own t-loads done) then s_barrier -> after barrier all t-data resident.
//   - stage(t+3) overwrites buf (t-1)&3: all reads of that buf completed before
//     MFMA(t-1) issued (lgkm dep), which precedes barrier(t); stage issues after.
//   Inside the window: 12 ds_read_b128 + 4 global_load_lds + 32 MFMA coexist, so
//   LDS reads overlap the other wave's MFMA burst (2 waves/SIMD drift freely).
// Counted vmcnt: steady 8 (tiles t+1,t+2 in flight), 4 at nkt-2, 0 at nkt-1.
// Requires: M%256==0, N%256==0, K%32==0, K>=96, grid%8==0.
template <int EPI>
__global__ __launch_bounds__(512, 2) void gemm256_nt(
    const unsigned short* __restrict__ A, int lda,
    const unsigned short* __restrict__ Bt, int ldb,
    void* __restrict__ Cb, int ldc,
    int kdim, int nbx,
    const float* __restrict__ resid, unsigned short* __restrict__ vt) {

    __shared__ unsigned short lds[4][2][8192];   // [ring buf][A,B][256 rows x 32 k] = 128 KiB

    // XCD-aware bijective block swizzle (grid % 8 == 0)
    unsigned id = blockIdx.x;
    unsigned nwg = gridDim.x;
    unsigned wg = (id & 7u) * (nwg >> 3) + (id >> 3);
    int bx = (int)(wg % (unsigned)nbx), by = (int)(wg / (unsigned)nbx);
    int m0 = by * 256, n0 = bx * 256;

    int tid = threadIdx.x;
    int wave = tid >> 6, lane = tid & 63;
    int quad = lane >> 4, l16 = lane & 15;
    int wr = wave >> 2, wc = wave & 3;           // 2 x 4 wave grid; per-wave C = 128 x 64

    // read-side swizzled lane offset: S(row,quad) = (row*64+quad*16) ^ ((row&7)<<4)
    int laneoff = (l16 * 64 + quad * 16) ^ ((l16 & 7) << 4);

    // stage-side inverse swizzle: thread tid fills linear LDS bytes [tid*16, tid*16+16)
    int q = tid >> 2;
    int rsw = q ^ ((q >> 2) & 1);                // source row (within 128-row half)
    int scol = ((tid & 3) ^ (rsw & 3)) << 3;     // source k-start (elements)
    const unsigned short* gA0 = A + (size_t)(m0 + rsw) * lda + scol;
    const unsigned short* gA1 = A + (size_t)(m0 + 128 + rsw) * lda + scol;
    const unsigned short* gB0 = Bt + (size_t)(n0 + rsw) * ldb + scol;
    const unsigned short* gB1 = Bt + (size_t)(n0 + 128 + rsw) * ldb + scol;

    int nkt = kdim >> 5;                         // K tiles of 32

    // prologue: stage tiles 0..2 into bufs 0..2 (FIFO order matters for vmcnt ledger)
#pragma unroll
    for (int u = 0; u < 3; ++u) {
        if (u < nkt) {
            char* dA = (char*)&lds[u][0][0] + wave * 1024;
            char* dB = (char*)&lds[u][1][0] + wave * 1024;
            gload_lds16(gA0 + u * 32, dA);
            gload_lds16(gA1 + u * 32, dA + 8192);
            gload_lds16(gB0 + u * 32, dB);
            gload_lds16(gB1 + u * 32, dB + 8192);
        }
    }
    gA0 += 96; gA1 += 96; gB0 += 96; gB1 += 96;  // next tile to stage = 3

    f32x4 acc[8][4] = {};

    for (int t = 0; t < nkt; ++t) {
        int buf = t & 3, sbuf = (t + 3) & 3;
        const char* lA = (const char*)&lds[buf][0][0];
        const char* lB = (const char*)&lds[buf][1][0];
        bool do_stage = (t + 3 < nkt);

        // own tile-t loads complete, then barrier -> all waves' tile-t data resident
        if (t + 2 < nkt)      asm volatile("s_waitcnt vmcnt(8)" ::: "memory");
        else if (t + 1 < nkt) asm volatile("s_waitcnt vmcnt(4)" ::: "memory");
        else                  asm volatile("s_waitcnt vmcnt(0)" ::: "memory");
        __builtin_amdgcn_s_barrier();
        __builtin_amdgcn_sched_barrier(0);       // pin: no ds_read hoists above the barrier

        short8 af[4], bfr[4], ag[4];
#pragma unroll
        for (int i = 0; i < 4; ++i)
            af[i] = *(const short8*)(lA + wr * 8192 + i * 1024 + laneoff);
#pragma unroll
        for (int j = 0; j < 4; ++j)
            bfr[j] = *(const short8*)(lB + wc * 4096 + j * 1024 + laneoff);
        if (do_stage) {
            char* dA = (char*)&lds[sbuf][0][0] + wave * 1024;
            gload_lds16(gA0, dA);
            gload_lds16(gA1, dA + 8192);
        }
#pragma unroll
        for (int i = 0; i < 4; ++i)
            ag[i] = *(const short8*)(lA + wr * 8192 + (4 + i) * 1024 + laneoff);
        if (do_stage) {
            char* dB = (char*)&lds[sbuf][1][0] + wave * 1024;
            gload_lds16(gB0, dB);
            gload_lds16(gB1, dB + 8192);
        }
        __builtin_amdgcn_s_setprio(1);
#pragma unroll
        for (int i = 0; i < 4; ++i)
#pragma unroll
            for (int j = 0; j < 4; ++j)
                acc[i][j] = __builtin_amdgcn_mfma_f32_16x16x32_bf16(af[i], bfr[j], acc[i][j], 0, 0, 0);
#pragma unroll
        for (int i = 0; i < 4; ++i)
#pragma unroll
            for (int j = 0; j < 4; ++j)
                acc[4 + i][j] = __builtin_amdgcn_mfma_f32_16x16x32_bf16(ag[i], bfr[j], acc[4 + i][j], 0, 0, 0);
        __builtin_amdgcn_s_setprio(0);

        gA0 += 32; gA1 += 32; gB0 += 32; gB1 += 32;
    }

    // ---- epilogue ----
    if (EPI == 3 && n0 >= 4096) {
        // v columns: transposed into vt[batch][kcol][s], packed 4 s-values
        int batch = m0 >> 11;
        int sl0 = (m0 & 2047) + wr * 128 + quad * 4;
#pragma unroll
        for (int j = 0; j < 4; ++j) {
            int kcol = (n0 - 4096) + wc * 64 + j * 16 + l16;
            unsigned short* base = vt + (size_t)batch * S_LEN * S_LEN + (size_t)kcol * S_LEN + sl0;
#pragma unroll
            for (int i = 0; i < 8; ++i) {
                ushort4v p;
#pragma unroll
                for (int r = 0; r < 4; ++r) p[r] = f2bf(acc[i][j][r]);
                *(ushort4v*)(base + i * 16) = p;
            }
        }
    } else if (EPI == 3) {
        unsigned short* C = (unsigned short*)Cb;
#pragma unroll
        for (int i = 0; i < 8; ++i)
#pragma unroll
            for (int r = 0; r < 4; ++r) {
                int row = m0 + wr * 128 + i * 16 + quad * 4 + r;
#pragma unroll
                for (int j = 0; j < 4; ++j)
                    C[(size_t)row * ldc + n0 + wc * 64 + j * 16 + l16] = f2bf(acc[i][j][r]);
            }
    } else { // EPI == 2: fp32 + residual
        float* C = (float*)Cb;
#pragma unroll
        for (int i = 0; i < 8; ++i)
#pragma unroll
            for (int r = 0; r < 4; ++r) {
                int row = m0 + wr * 128 + i * 16 + quad * 4 + r;
#pragma unroll
                for (int j = 0; j < 4; ++j) {
                    int col = n0 + wc * 64 + j * 16 + l16;
                    C[(size_t)row * ldc + col] = acc[i][j][r] + resid[(size_t)row * ldc + col];
                }
            }
    }
}

extern "C" void kernel_launch(void* const* d_in, const int* in_sizes, int n_in,
                              void* d_out, int out_size, void* d_ws, size_t ws_size,
                              hipStream_t stream) {
    const float* x      = (const float*)d_in[0];   // [4,2048,2048]
    const float* qkv    = (const float*)d_in[1];   // [2048,6144]
    const float* o_proj = (const float*)d_in[2];   // [2048,2048]
    const float* gamma  = (const float*)d_in[3];
    const float* beta   = (const float*)d_in[4];
    float* out = (float*)d_out;                    // [8192,2048]

    char* w = (char*)d_ws;
    unsigned short* xn      = (unsigned short*)(w);              // 33,554,432 B [8192,2048]; later aliased as scores
    unsigned short* w_t     = (unsigned short*)(w + 33554432);   // 25,165,824 B [6144,2048] qkv^T
    unsigned short* o_t     = (unsigned short*)(w + 58720256);   //  8,388,608 B [2048,2048] o_proj^T
    unsigned short* qkv_out = (unsigned short*)(w + 67108864);   // 100,663,296 B [8192,6144] q|k (v slot unused; q slot reused for attn_out)
    unsigned short* v_t     = (unsigned short*)(w + 167772160);  // 33,554,432 B [4][2048,2048] v^T (written directly by GEMM1)
    unsigned short* scores  = xn;                                // alias: x_norm dead after GEMM1

    // 1) LayerNorm + cast
    ln_kernel<<<NROWS, 256, 0, stream>>>(x, gamma, beta, xn);
    // 2) weight transposes + cast
    transp_f32_bf16<<<dim3(192, 64), 256, 0, stream>>>(qkv, N3, w_t, HD);
    transp_f32_bf16<<<dim3(64, 64), 256, 0, stream>>>(o_proj, HD, o_t, HD);
    // 3) QKV projection: [8192,2048] @ [2048,6144] via 256^2 pipelined GEMM
    //    q,k row-major bf16, v written transposed to v_t.  grid = 24x32 = 768 (%8==0)
    gemm256_nt<3><<<dim3(768), 512, 0, stream>>>(xn, HD, w_t, HD,
        (void*)qkv_out, N3, HD, 24, nullptr, v_t);
    // 4) scores = q @ k^T * scale (skip upper-triangle blocks, longest rows first)
    float scale = 0.022097086912079608f; // 1/sqrt(2048)
    gemm_nt<1><<<dim3(16, 16, 4), 256, 0, stream>>>(qkv_out, N3, (long)S_LEN * N3,
        qkv_out + 2048, N3, (long)S_LEN * N3,
        (void*)scores, S_LEN, (long)S_LEN * S_LEN, HD, 1, scale, nullptr, nullptr);
    // 5) causal softmax in place (zeroes t>s so PV GEMM reads clean zeros)
    softmax_causal<<<NROWS, 256, 0, stream>>>(scores);
    // 6) attn_out = P @ V  (K clipped at diagonal block, longest-first), into q slot of qkv_out
    gemm_nt<0><<<dim3(16, 16, 4), 256, 0, stream>>>(scores, S_LEN, (long)S_LEN * S_LEN,
        v_t, S_LEN, (long)HD * S_LEN,
        (void*)qkv_out, N3, (long)S_LEN * N3, S_LEN, 2, 1.0f, nullptr, nullptr);
    // 7) out = attn_out @ o_proj + x (fp32) via 256^2 pipelined GEMM; grid = 8x32 = 256
    gemm256_nt<2><<<dim3(256), 512, 0, stream>>>(qkv_out, N3, o_t, HD,
        (void*)out, HD, HD, 8, x, nullptr);
}